// Round 9
// baseline (226.322 us; speedup 1.0000x reference)
//
#include <hip/hip_runtime.h>

// Fused GNN forward for mynet_30039001268550 on gfx950 — round 9.
// vs R8 (124.6 us, VALU-bound at 73%):
//  - xa lives in LDS as TWO bf16 planes (hi/lo truncation split) -> stage-A
//    A-fragments are raw ds_read_b128, zero split/repack VALU (was ~160
//    ops/lane/layer of split2).
//  - es/ed computed on the MFMA pipe: B-frag with cols 0/1 = was'/wad'
//    (split-bf16, prepped into d_ws), reusing stage-A's A-fragments; the old
//    fp32 matvec (~90 ops/lane/layer) is gone. MFMA pipe was 6% busy - free.
//  - h stored as per-wave hi/lo bf16 planes -> stage-B B-frag = 2x b128,
//    zero unpack.
//  - strides: xa planes 72 shorts (36 dw = 4 mod 32), hT 40 shorts -> uniform
//    bank-group coverage (R8 lesson).

#define NGRAPH 4096
#define EDGES  (NGRAPH * 256)
#define NT     256
#define LOG2E  1.4426950408889634f

typedef __attribute__((ext_vector_type(8))) short bf16x8;
typedef __attribute__((ext_vector_type(4))) float f32x4;
typedef __attribute__((ext_vector_type(4))) int   i32x4;

__device__ __forceinline__ unsigned f2u(float x){ union{float f;unsigned u;}c;c.f=x;return c.u; }
__device__ __forceinline__ float u2f(unsigned u){ union{unsigned u;float f;}c;c.u=u;return c.f; }

// split two fp32 into packed-bf16 hi dword and lo dword (truncation split)
__device__ __forceinline__ void split2(float x0, float x1, unsigned& dhi, unsigned& dlo){
    const unsigned u0 = f2u(x0), u1 = f2u(x1);
    dhi = (u0 >> 16) | (u1 & 0xffff0000u);
    const float l0 = x0 - u2f(u0 & 0xffff0000u);
    const float l1 = x1 - u2f(u1 & 0xffff0000u);
    dlo = (f2u(l0) >> 16) | (f2u(l1) & 0xffff0000u);
}

__device__ __forceinline__ f32x4 mfma16(i32x4 a, i32x4 b, f32x4 c){
    return __builtin_amdgcn_mfma_f32_16x16x32_bf16(
        __builtin_bit_cast(bf16x8, a), __builtin_bit_cast(bf16x8, b), c, 0, 0, 0);
}

// ws layout (bytes):
//   0      : Wt planes per layer l at l*16384: hi [64n][64k] bf16 (8192), lo +8192
//   65536  : esed tiles per (l,w) at (l*4+w)*4096: hi [16n][64k] bf16 (2048), lo +2048
//            rows n=0 -> was'*log2e, n=1 -> wad'*log2e, rest 0
template<int KSTEPS>
__device__ __forceinline__ void gat_layer(
    int tid, unsigned short (*xh)[72], unsigned short (*xl)[72],
    unsigned short* hh_w, unsigned short* hl_w, float* esw, float* edw,
    const unsigned char* A8, const char* __restrict__ ws, int l,
    const float* __restrict__ b_g)
{
    const int lane = tid & 63, w = tid >> 6;
    const int n15 = lane & 15, q = lane >> 4;

    // ---- stage A: h = xa@W and es/ed = xa@[was' wad'] on MFMA ----
    f32x4 hC0 = {0,0,0,0}, hC1 = {0,0,0,0};
    f32x4 eC0 = {0,0,0,0}, eC1 = {0,0,0,0};
#pragma unroll
    for (int ks = 0; ks < KSTEPS; ++ks){
        const unsigned short* wr = (const unsigned short*)(ws + l*16384)
                                   + (w*16 + n15)*64 + ks*32 + q*8;
        const i32x4 bh = *(const i32x4*)wr;
        const i32x4 bl = *(const i32x4*)(wr + 4096);
        const unsigned short* er = (const unsigned short*)(ws + 65536)
                                   + (l*4 + w)*2048 + n15*64 + ks*32 + q*8;
        const i32x4 eh = *(const i32x4*)er;
        const i32x4 el = *(const i32x4*)(er + 1024);

        const i32x4 a0h = *(const i32x4*)&xh[n15][ks*32 + q*8];
        const i32x4 a0l = *(const i32x4*)&xl[n15][ks*32 + q*8];
        hC0 = mfma16(a0h, bh, hC0); hC0 = mfma16(a0h, bl, hC0); hC0 = mfma16(a0l, bh, hC0);
        eC0 = mfma16(a0h, eh, eC0); eC0 = mfma16(a0h, el, eC0); eC0 = mfma16(a0l, eh, eC0);

        const i32x4 a1h = *(const i32x4*)&xh[16 + n15][ks*32 + q*8];
        const i32x4 a1l = *(const i32x4*)&xl[16 + n15][ks*32 + q*8];
        hC1 = mfma16(a1h, bh, hC1); hC1 = mfma16(a1h, bl, hC1); hC1 = mfma16(a1l, bh, hC1);
        eC1 = mfma16(a1h, eh, eC1); eC1 = mfma16(a1h, el, eC1); eC1 = mfma16(a1l, eh, eC1);
    }
    __syncthreads();   // all xa reads done; wave-local work + xa writes follow

    // ---- scatter es/ed (C-layout: col 0 = es, col 1 = ed) to LDS ----
    if (n15 < 2){
        float* dst = n15 ? edw : esw;
#pragma unroll
        for (int r = 0; r < 4; ++r){
            dst[q*4 + r]      = eC0[r];
            dst[16 + q*4 + r] = eC1[r];
        }
    }

    // ---- pack h (hi/lo bf16 planes, [n][k=j] order for stage-B B-frag) ----
#pragma unroll
    for (int mt = 0; mt < 2; ++mt){
        const f32x4 hv = mt ? hC1 : hC0;
#pragma unroll
        for (int r = 0; r < 4; ++r){
            const float xv = hv[r];
            const unsigned u = f2u(xv);
            const float lo = xv - u2f(u & 0xffff0000u);
            hh_w[n15*40 + mt*16 + q*4 + r] = (unsigned short)(u >> 16);
            hl_w[n15*40 + mt*16 + q*4 + r] = (unsigned short)(f2u(lo) >> 16);
        }
    }

    // ---- p build, both m-tiles, directly in A-frag layout (m=n15, k=q*8+jj) ----
    float pf0[8], pf1[8];
    {
        float es8[8];
        *(float4*)&es8[0] = *(const float4*)&esw[q*8];
        *(float4*)&es8[4] = *(const float4*)&esw[q*8 + 4];
        const float ed0 = edw[n15], ed1 = edw[16 + n15];
        const uint2 c0 = *(const uint2*)&A8[n15*40 + q*8];
        const uint2 c1 = *(const uint2*)&A8[(16 + n15)*40 + q*8];
        float ss0 = 0.f, ss1 = 0.f;
#pragma unroll
        for (int jj = 0; jj < 8; ++jj){
            const unsigned cnt0 = ((jj < 4 ? c0.x >> (8*jj) : c0.y >> (8*(jj-4))) & 0xffu);
            const unsigned cnt1 = ((jj < 4 ? c1.x >> (8*jj) : c1.y >> (8*(jj-4))) & 0xffu);
            float e0 = es8[jj] + ed0; e0 = fmaxf(e0, 0.2f*e0);   // lrelu, log2-domain
            float e1 = es8[jj] + ed1; e1 = fmaxf(e1, 0.2f*e1);
            const float p0 = (float)cnt0 * exp2f(e0);
            const float p1 = (float)cnt1 * exp2f(e1);
            pf0[jj] = p0; ss0 += p0;
            pf1[jj] = p1; ss1 += p1;
        }
        ss0 += __shfl_xor(ss0, 16); ss0 += __shfl_xor(ss0, 32);
        ss1 += __shfl_xor(ss1, 16); ss1 += __shfl_xor(ss1, 32);
        // inv overlays edw (all edw reads above complete, wave-local)
        if (q == 0){
            edw[n15]      = 1.f/(ss0 + 1e-16f);
            edw[16 + n15] = 1.f/(ss1 + 1e-16f);
        }
    }

    // ---- stage B: out = P@h via mfma (B-frag = raw b128 from h planes) ----
    {
        const i32x4 bh = *(const i32x4*)&hh_w[n15*40 + q*8];
        const i32x4 bl = *(const i32x4*)&hl_w[n15*40 + q*8];
        f32x4 o0 = {0,0,0,0}, o1 = {0,0,0,0};
        i32x4 ph, pl; unsigned th, tl;
#pragma unroll
        for (int r = 0; r < 4; ++r){
            split2(pf0[2*r], pf0[2*r+1], th, tl); ph[r] = (int)th; pl[r] = (int)tl;
        }
        o0 = mfma16(ph, bh, o0); o0 = mfma16(ph, bl, o0); o0 = mfma16(pl, bh, o0);
#pragma unroll
        for (int r = 0; r < 4; ++r){
            split2(pf1[2*r], pf1[2*r+1], th, tl); ph[r] = (int)th; pl[r] = (int)tl;
        }
        o1 = mfma16(ph, bh, o1); o1 = mfma16(ph, bl, o1); o1 = mfma16(pl, bh, o1);

        const float bv = __ldg(b_g + w*16 + n15);
#pragma unroll
        for (int mt = 0; mt < 2; ++mt){
            const f32x4 ov = mt ? o1 : o0;
#pragma unroll
            for (int r = 0; r < 4; ++r){
                const int row = mt*16 + q*4 + r;
                float v = ov[r] * edw[row] + bv;
                v = fmaxf(v, 0.01f*v);
                const unsigned u = f2u(v);
                const float lo = v - u2f(u & 0xffff0000u);
                xh[row][w*16 + n15] = (unsigned short)(u >> 16);
                xl[row][w*16 + n15] = (unsigned short)(f2u(lo) >> 16);
            }
        }
    }
}

__global__ __launch_bounds__(NT) void gnn_fused(
    const float* __restrict__ x, const int* __restrict__ edge_index,
    const float* __restrict__ Wq, const float* __restrict__ Wk, const float* __restrict__ Wv,
    const float* __restrict__ b1, const float* __restrict__ b2,
    const float* __restrict__ b3, const float* __restrict__ b4,
    const float* __restrict__ fcW, const float* __restrict__ fcb,
    const char* __restrict__ ws, float* __restrict__ out)
{
    __shared__ __align__(16) unsigned short xap[2][32][72]; // bf16 hi/lo feature planes
    __shared__ __align__(16) unsigned short hT[4][2][16][40]; // per-wave h planes / attn scratch
    __shared__ __align__(16) float es_l[4][32];
    __shared__ __align__(16) float ed_l[4][32];
    __shared__ __align__(16) unsigned char A8[32*40];

    const int g = blockIdx.x, tid = threadIdx.x;
    const int w = tid >> 6;
    int* A32 = (int*)&xap[0][0][0];        // transient build area (4 KB <= 4.6 KB plane)
    float* scr = (float*)&hT[0][0][0][0];  // attn scratch (5936 B <= 10240 B)
    float* xin = scr;            // [32][12]
    float* qkv = scr + 384;      // [3][10][33]
    float* sc  = scr + 1374;     // [10][11]

    // phase 0: zero A32, stage x
    for (int idx = tid; idx < 1024; idx += NT) A32[idx] = 0;
    for (int idx = tid; idx < 320; idx += NT)
        xin[(idx/10)*12 + (idx%10)] = x[g*320 + idx];
    __syncthreads();

    // phase 1: edge-count atomics + Q/K/V GEMMs
    {
        const int* dstp = edge_index + EDGES + g*256;
        atomicAdd(&A32[(dstp[tid] & 31)*32 + (tid >> 3)], 1);
        if (tid < 32) atomicAdd(&A32[tid*33], 1);     // PyG self-loops
    }
    for (int idx = tid; idx < 960; idx += NT){
        const int mat = idx/320, r = idx - mat*320, s = r >> 5, i = r & 31;
        const float* Wsrc = (mat == 0) ? Wq : ((mat == 1) ? Wk : Wv);
        float acc = 0.f;
#pragma unroll
        for (int mm = 0; mm < 32; ++mm) acc += xin[mm*12 + s]*__ldg(Wsrc + mm*32 + i);
        qkv[mat*330 + s*33 + i] = acc;
    }
    __syncthreads();

    // phase 2a: 10x10 scores
    if (tid < 100){
        const int s = tid/10, t = tid - 10*(tid/10);
        const float* qs = qkv + s*33;
        const float* kt = qkv + 330 + t*33;
        float acc = 0.f;
#pragma unroll
        for (int i2 = 0; i2 < 32; ++i2) acc += qs[i2]*kt[i2];
        sc[s*11 + t] = acc;
    }
    __syncthreads();

    // phase 2b: A8 pack + row softmax
    {
        const int i = tid >> 3, j4 = (tid & 7)*4;
        const int4 v = *(const int4*)&A32[i*32 + j4];
        *(unsigned*)&A8[i*40 + j4] =
            (unsigned)v.x | ((unsigned)v.y << 8) | ((unsigned)v.z << 16) | ((unsigned)v.w << 24);
    }
    if (tid < 10){
        float* row = sc + tid*11;
        float m = row[0];
#pragma unroll
        for (int t = 1; t < 10; ++t) m = fmaxf(m, row[t]);
        float ssum = 0.f;
#pragma unroll
        for (int t = 0; t < 10; ++t){ const float e = __expf(row[t]-m); row[t] = e; ssum += e; }
        const float inv = 1.f/ssum;
#pragma unroll
        for (int t = 0; t < 10; ++t) row[t] *= inv;
    }
    __syncthreads();

    // phase 3: attention out -> xa planes (transposed, split-bf16, zero-pad 10..63)
    for (int idx = tid; idx < 2048; idx += NT){
        const int i = idx >> 6, s = idx & 63;
        float acc = 0.f;
        if (s < 10){
#pragma unroll
            for (int t = 0; t < 10; ++t) acc += sc[s*11 + t]*qkv[660 + t*33 + i];
        }
        const unsigned u = f2u(acc);
        const float lo = acc - u2f(u & 0xffff0000u);
        xap[0][i][s] = (unsigned short)(u >> 16);
        xap[1][i][s] = (unsigned short)(f2u(lo) >> 16);
    }
    __syncthreads();

    unsigned short (*xh)[72] = xap[0];
    unsigned short (*xl)[72] = xap[1];
    unsigned short* hh_w = &hT[w][0][0][0];
    unsigned short* hl_w = &hT[w][1][0][0];
    float* esw = es_l[w];
    float* edw = ed_l[w];
    gat_layer<1>(tid, xh, xl, hh_w, hl_w, esw, edw, A8, ws, 0, b1);
    __syncthreads();
    gat_layer<2>(tid, xh, xl, hh_w, hl_w, esw, edw, A8, ws, 1, b2);
    __syncthreads();
    gat_layer<2>(tid, xh, xl, hh_w, hl_w, esw, edw, A8, ws, 2, b3);
    __syncthreads();
    gat_layer<2>(tid, xh, xl, hh_w, hl_w, esw, edw, A8, ws, 3, b4);
    __syncthreads();

    // mean pool (reconstruct hi+lo) + FC(64->2) + softmax
    if (tid < 64){
        float acc = 0.f;
#pragma unroll
        for (int n = 0; n < 32; ++n)
            acc += u2f(((unsigned)xap[0][n][tid]) << 16) + u2f(((unsigned)xap[1][n][tid]) << 16);
        const float p = acc*(1.f/32.f);
        float c0 = p*__ldg(fcW + 2*tid);
        float c1 = p*__ldg(fcW + 2*tid + 1);
#pragma unroll
        for (int off = 32; off > 0; off >>= 1){
            c0 += __shfl_down(c0, off);
            c1 += __shfl_down(c1, off);
        }
        if (tid == 0){
            const float l0 = c0 + __ldg(fcb), l1 = c1 + __ldg(fcb + 1);
            const float m = fmaxf(l0, l1);
            const float e0 = __expf(l0 - m), e1 = __expf(l1 - m);
            const float inv = 1.f/(e0 + e1);
            out[2*g] = l0;
            out[2*g + 1] = l1;
            out[2*NGRAPH + 2*g] = e0*inv;
            out[2*NGRAPH + 2*g + 1] = e1*inv;
        }
    }
}

// prep: split-bf16 W^T planes + esed tiles (cols 0/1 = (W@a_s/d)*log2e) into d_ws.
__global__ void prep(
    const float* __restrict__ W1, const float* __restrict__ W2,
    const float* __restrict__ W3, const float* __restrict__ W4,
    const float* __restrict__ a1s, const float* __restrict__ a1d,
    const float* __restrict__ a2s, const float* __restrict__ a2d,
    const float* __restrict__ a3s, const float* __restrict__ a3d,
    const float* __restrict__ a4s, const float* __restrict__ a4d,
    char* __restrict__ ws)
{
    const int b = blockIdx.x, tid = threadIdx.x;
    const float* Wl[4] = {W1, W2, W3, W4};
    const int Kl[4] = {10, 64, 64, 64};
    if (b < 32){
        const int l = b >> 3;
        const float* W = Wl[l];
        const int K = Kl[l];
        unsigned short* hi = (unsigned short*)(ws + l*16384);
        unsigned short* lo = hi + 4096;
        const int base = (b & 7)*512;
        for (int idx = base + tid; idx < base + 512; idx += NT){
            const int n = idx >> 6, k = idx & 63;
            const float v = (k < K) ? __ldg(W + k*64 + n) : 0.f;
            const unsigned u = f2u(v);
            const float lof = v - u2f(u & 0xffff0000u);
            hi[idx] = (unsigned short)(u >> 16);
            lo[idx] = (unsigned short)(f2u(lof) >> 16);
        }
    } else {
        const int l = b - 32;
        const float* W = Wl[l];
        const int K = Kl[l];
        const float* asp[4] = {a1s, a2s, a3s, a4s};
        const float* adp[4] = {a1d, a2d, a3d, a4d};
        const int C = (l < 3) ? 16 : 64;
        unsigned short* base = (unsigned short*)(ws + 65536);
        for (int idx = tid; idx < 4096; idx += NT){
            const int wv = idx >> 10, rem = idx & 1023, n = rem >> 6, k = rem & 63;
            float val = 0.f;
            if (n < 2 && k < K){
                const int hh = (l < 3) ? wv : 0;
                const float* av = n ? adp[l] : asp[l];
                float s = 0.f;
                for (int c = 0; c < C; ++c)
                    s += __ldg(W + k*64 + hh*C + c) * __ldg(av + hh*C + c);
                val = s * LOG2E;
            }
            const unsigned u = f2u(val);
            const float lof = val - u2f(u & 0xffff0000u);
            base[(l*4 + wv)*2048 + n*64 + k] = (unsigned short)(u >> 16);
            base[(l*4 + wv)*2048 + 1024 + n*64 + k] = (unsigned short)(f2u(lof) >> 16);
        }
    }
}

extern "C" void kernel_launch(void* const* d_in, const int* in_sizes, int n_in,
                              void* d_out, int out_size, void* d_ws, size_t ws_size,
                              hipStream_t stream) {
    (void)in_sizes; (void)n_in; (void)ws_size; (void)out_size;
    prep<<<36, NT, 0, stream>>>(
        (const float*)d_in[6], (const float*)d_in[10], (const float*)d_in[14], (const float*)d_in[18],
        (const float*)d_in[7], (const float*)d_in[8],
        (const float*)d_in[11], (const float*)d_in[12],
        (const float*)d_in[15], (const float*)d_in[16],
        (const float*)d_in[19], (const float*)d_in[20],
        (char*)d_ws);
    gnn_fused<<<NGRAPH, NT, 0, stream>>>(
        (const float*)d_in[0], (const int*)d_in[1],
        (const float*)d_in[3], (const float*)d_in[4], (const float*)d_in[5],
        (const float*)d_in[9], (const float*)d_in[13], (const float*)d_in[17], (const float*)d_in[21],
        (const float*)d_in[22], (const float*)d_in[23],
        (const char*)d_ws, (float*)d_out);
}

// Round 12
// 203.145 us; speedup vs baseline: 1.1141x; 1.1141x over previous
//
#include <hip/hip_runtime.h>

// Fused GNN forward for mynet_30039001268550 on gfx950 — round 12.
// R11 + fix: phase 0 now ZEROES x^T feature-rows 10..15 (both bf16 planes).
// R10/R11 left those rows as stale LDS; the QKV MFMA A-fragment reads rows
// 0..15, so stale Inf/NaN bf16 patterns produced 0*Inf=NaN that survived the
// masked softmax (R11 first-launch NaN; nondeterministic by prior LDS
// content). R10's post-timing 0.27 was the separate d_ws overflow, fixed in
// R11 (footprint 94208 B < proven-safe 131072).

#define NGRAPH 4096
#define EDGES  (NGRAPH * 256)
#define NT     256
#define LOG2E  1.4426950408889634f

typedef __attribute__((ext_vector_type(8))) short bf16x8;
typedef __attribute__((ext_vector_type(4))) float f32x4;
typedef __attribute__((ext_vector_type(4))) int   i32x4;

__device__ __forceinline__ unsigned f2u(float x){ union{float f;unsigned u;}c;c.f=x;return c.u; }
__device__ __forceinline__ float u2f(unsigned u){ union{unsigned u;float f;}c;c.u=u;return c.f; }

__device__ __forceinline__ void split2(float x0, float x1, unsigned& dhi, unsigned& dlo){
    const unsigned u0 = f2u(x0), u1 = f2u(x1);
    dhi = (u0 >> 16) | (u1 & 0xffff0000u);
    const float l0 = x0 - u2f(u0 & 0xffff0000u);
    const float l1 = x1 - u2f(u1 & 0xffff0000u);
    dlo = (f2u(l0) >> 16) | (f2u(l1) & 0xffff0000u);
}

__device__ __forceinline__ f32x4 mfma16(i32x4 a, i32x4 b, f32x4 c){
    return __builtin_amdgcn_mfma_f32_16x16x32_bf16(
        __builtin_bit_cast(bf16x8, a), __builtin_bit_cast(bf16x8, b), c, 0, 0, 0);
}

// ws layout (bytes), total 94208 <= proven-safe 131072:
//   0     : Wt planes per layer l at l*16384: hi [64n][64k] bf16, lo +8192
//   65536 : esed shared tile per layer at 65536+l*4096: hi [16n][64k], lo +2048
//           rows 2h -> was'_h*log2e, 2h+1 -> wad'_h*log2e (l=3: head 0 dup), rest 0
//   81920 : QKV^T planes per mat at 81920+mat*4096: hi [32 i][32 m], lo +2048
template<int KSTEPS>
__device__ __forceinline__ void gat_layer(
    int tid, unsigned short (*xh)[72], unsigned short (*xl)[72],
    unsigned short* hh_w, unsigned short* hl_w, float* esw, float* edw,
    const unsigned int* Ap, const char* __restrict__ ws, int l,
    const float* __restrict__ b_g)
{
    const int lane = tid & 63, w = tid >> 6;
    const int n15 = lane & 15, q = lane >> 4;

    // ---- stage A: h = xa@W and es/ed (all heads) = xa@esed-tile on MFMA ----
    f32x4 hC0 = {0,0,0,0}, hC1 = {0,0,0,0};
    f32x4 eC0 = {0,0,0,0}, eC1 = {0,0,0,0};
#pragma unroll
    for (int ks = 0; ks < KSTEPS; ++ks){
        const unsigned short* wr = (const unsigned short*)(ws + l*16384)
                                   + (w*16 + n15)*64 + ks*32 + q*8;
        const i32x4 bh = *(const i32x4*)wr;
        const i32x4 bl = *(const i32x4*)(wr + 4096);
        const unsigned short* er = (const unsigned short*)(ws + 65536 + l*4096)
                                   + n15*64 + ks*32 + q*8;
        const i32x4 eh = *(const i32x4*)er;
        const i32x4 el = *(const i32x4*)(er + 1024);

        const i32x4 a0h = *(const i32x4*)&xh[n15][ks*32 + q*8];
        const i32x4 a0l = *(const i32x4*)&xl[n15][ks*32 + q*8];
        hC0 = mfma16(a0h, bh, hC0); hC0 = mfma16(a0h, bl, hC0); hC0 = mfma16(a0l, bh, hC0);
        eC0 = mfma16(a0h, eh, eC0); eC0 = mfma16(a0h, el, eC0); eC0 = mfma16(a0l, eh, eC0);

        const i32x4 a1h = *(const i32x4*)&xh[16 + n15][ks*32 + q*8];
        const i32x4 a1l = *(const i32x4*)&xl[16 + n15][ks*32 + q*8];
        hC1 = mfma16(a1h, bh, hC1); hC1 = mfma16(a1h, bl, hC1); hC1 = mfma16(a1l, bh, hC1);
        eC1 = mfma16(a1h, eh, eC1); eC1 = mfma16(a1h, el, eC1); eC1 = mfma16(a1l, eh, eC1);
    }
    __syncthreads();   // all xa reads done; wave-local work + xa writes follow

    // ---- scatter es/ed: this wave's head lives in C-columns 2w (es), 2w+1 (ed) ----
    if (n15 == 2*w || n15 == 2*w + 1){
        float* dst = (n15 & 1) ? edw : esw;
#pragma unroll
        for (int r = 0; r < 4; ++r){
            dst[q*4 + r]      = eC0[r];
            dst[16 + q*4 + r] = eC1[r];
        }
    }

    // ---- pack h (hi/lo bf16 planes, [n][k=j] order for stage-B B-frag) ----
#pragma unroll
    for (int mt = 0; mt < 2; ++mt){
        const f32x4 hv = mt ? hC1 : hC0;
#pragma unroll
        for (int r = 0; r < 4; ++r){
            const float xv = hv[r];
            const unsigned u = f2u(xv);
            const float lo = xv - u2f(u & 0xffff0000u);
            hh_w[n15*40 + mt*16 + q*4 + r] = (unsigned short)(u >> 16);
            hl_w[n15*40 + mt*16 + q*4 + r] = (unsigned short)(f2u(lo) >> 16);
        }
    }

    // ---- p build, both m-tiles, directly in A-frag layout (m=n15, k=q*8+jj) ----
    float pf0[8], pf1[8];
    {
        float es8[8];
        *(float4*)&es8[0] = *(const float4*)&esw[q*8];
        *(float4*)&es8[4] = *(const float4*)&esw[q*8 + 4];
        const float ed0 = edw[n15], ed1 = edw[16 + n15];
        const uint2 c0 = make_uint2(Ap[n15*9 + 2*q], Ap[n15*9 + 2*q + 1]);
        const uint2 c1 = make_uint2(Ap[(16+n15)*9 + 2*q], Ap[(16+n15)*9 + 2*q + 1]);
        float ss0 = 0.f, ss1 = 0.f;
#pragma unroll
        for (int jj = 0; jj < 8; ++jj){
            const unsigned cnt0 = ((jj < 4 ? c0.x >> (8*jj) : c0.y >> (8*(jj-4))) & 0xffu);
            const unsigned cnt1 = ((jj < 4 ? c1.x >> (8*jj) : c1.y >> (8*(jj-4))) & 0xffu);
            float e0 = es8[jj] + ed0; e0 = fmaxf(e0, 0.2f*e0);   // lrelu, log2-domain
            float e1 = es8[jj] + ed1; e1 = fmaxf(e1, 0.2f*e1);
            const float p0 = (float)cnt0 * exp2f(e0);
            const float p1 = (float)cnt1 * exp2f(e1);
            pf0[jj] = p0; ss0 += p0;
            pf1[jj] = p1; ss1 += p1;
        }
        ss0 += __shfl_xor(ss0, 16); ss0 += __shfl_xor(ss0, 32);
        ss1 += __shfl_xor(ss1, 16); ss1 += __shfl_xor(ss1, 32);
        if (q == 0){
            edw[n15]      = 1.f/(ss0 + 1e-16f);
            edw[16 + n15] = 1.f/(ss1 + 1e-16f);
        }
    }

    // ---- stage B: out = P@h via mfma (B-frag = raw b128 from h planes) ----
    {
        const i32x4 bh = *(const i32x4*)&hh_w[n15*40 + q*8];
        const i32x4 bl = *(const i32x4*)&hl_w[n15*40 + q*8];
        f32x4 o0 = {0,0,0,0}, o1 = {0,0,0,0};
        i32x4 ph, pl; unsigned th, tl;
#pragma unroll
        for (int r = 0; r < 4; ++r){
            split2(pf0[2*r], pf0[2*r+1], th, tl); ph[r] = (int)th; pl[r] = (int)tl;
        }
        o0 = mfma16(ph, bh, o0); o0 = mfma16(ph, bl, o0); o0 = mfma16(pl, bh, o0);
#pragma unroll
        for (int r = 0; r < 4; ++r){
            split2(pf1[2*r], pf1[2*r+1], th, tl); ph[r] = (int)th; pl[r] = (int)tl;
        }
        o1 = mfma16(ph, bh, o1); o1 = mfma16(ph, bl, o1); o1 = mfma16(pl, bh, o1);

        const float bv = __ldg(b_g + w*16 + n15);
#pragma unroll
        for (int mt = 0; mt < 2; ++mt){
            const f32x4 ov = mt ? o1 : o0;
#pragma unroll
            for (int r = 0; r < 4; ++r){
                const int row = mt*16 + q*4 + r;
                float v = ov[r] * edw[row] + bv;
                v = fmaxf(v, 0.01f*v);
                const unsigned u = f2u(v);
                const float lo = v - u2f(u & 0xffff0000u);
                xh[row][w*16 + n15] = (unsigned short)(u >> 16);
                xl[row][w*16 + n15] = (unsigned short)(f2u(lo) >> 16);
            }
        }
    }
}

__global__ __launch_bounds__(NT) void gnn_fused(
    const float* __restrict__ x, const int* __restrict__ edge_index,
    const float* __restrict__ b1, const float* __restrict__ b2,
    const float* __restrict__ b3, const float* __restrict__ b4,
    const float* __restrict__ fcW, const float* __restrict__ fcb,
    const char* __restrict__ ws, float* __restrict__ out)
{
    __shared__ __align__(16) unsigned short xap[2][32][72]; // bf16 hi/lo feature planes
    __shared__ __align__(16) unsigned short hT[4][2][16][40]; // per-wave h planes / attn scratch
    __shared__ __align__(16) float es_l[4][32];
    __shared__ __align__(16) float ed_l[4][32];
    __shared__ __align__(16) unsigned int Ap[32*9];  // packed u8 edge counts

    const int g = blockIdx.x, tid = threadIdx.x;
    const int lane = tid & 63, w = tid >> 6;
    const int n15 = lane & 15, q = lane >> 4;

    // front-end overlays (short offsets)
    unsigned short* r0 = &xap[0][0][0];   // 4608 shorts
    //   XTH 0 [16s][40->m], XTL 640, QPH 1280, QPL 1920, KPH 2560, KPL 3200
    unsigned short* r1 = &hT[0][0][0][0]; // 5120 shorts
    //   VTH 0 [32 i][40 t], VTL 1280, SPH 2560 [16 s][40 t], SPL 3200

    // ---- phase 0: zero Ap, stage x^T (split-bf16), zero x^T rows 10..15 ----
    for (int idx = tid; idx < 288; idx += NT) Ap[idx] = 0u;
    for (int idx = tid; idx < 320; idx += NT){
        const int m = idx / 10, s = idx - 10*m;   // m = node, s = feat
        const float v = x[g*320 + idx];
        const unsigned u = f2u(v);
        const float lo = v - u2f(u & 0xffff0000u);
        r0[0   + s*40 + m] = (unsigned short)(u >> 16);
        r0[640 + s*40 + m] = (unsigned short)(f2u(lo) >> 16);
    }
    if (tid < 192){   // stale-LDS guard: rows 10..15 feed the QKV A-fragment
        const int s = 10 + (tid >> 5), m = tid & 31;
        r0[0   + s*40 + m] = 0;
        r0[640 + s*40 + m] = 0;
    }
    __syncthreads();

    // ---- P1: edge-count packed atomics + Q/K/V MFMA + V^T tail zero ----
    {
        const int* dstp = edge_index + EDGES + g*256;
        const int i = dstp[tid] & 31, j = tid >> 3;
        atomicAdd(&Ap[i*9 + (j >> 2)], 1u << (8*(j & 3)));
        if (tid < 32) atomicAdd(&Ap[tid*9 + (tid >> 2)], 1u << (8*(tid & 3)));
    }
    if (w < 3){
        const unsigned short* wb = (const unsigned short*)(ws + 81920 + w*4096);
        const i32x4 ah = *(const i32x4*)&r0[0   + n15*40 + q*8];
        const i32x4 al = *(const i32x4*)&r0[640 + n15*40 + q*8];
        f32x4 C0 = {0,0,0,0}, C1 = {0,0,0,0};
#pragma unroll
        for (int nt = 0; nt < 2; ++nt){
            const i32x4 bh = *(const i32x4*)&wb[(nt*16 + n15)*32 + q*8];
            const i32x4 bl = *(const i32x4*)&wb[1024 + (nt*16 + n15)*32 + q*8];
            f32x4 acc = nt ? C1 : C0;
            acc = mfma16(ah, bh, acc); acc = mfma16(ah, bl, acc); acc = mfma16(al, bh, acc);
            if (nt) C1 = acc; else C0 = acc;
        }
        if (w < 2){
            const int base = (w == 0) ? 1280 : 2560;  // QPH : KPH
#pragma unroll
            for (int nt = 0; nt < 2; ++nt){
                const f32x4 cv = nt ? C1 : C0;
                const int i = nt*16 + n15;
#pragma unroll
                for (int r = 0; r < 4; ++r){
                    const int s = q*4 + r;
                    const float v = cv[r];
                    const unsigned u = f2u(v);
                    const float lo = v - u2f(u & 0xffff0000u);
                    r0[base + s*40 + i]       = (unsigned short)(u >> 16);
                    r0[base + 640 + s*40 + i] = (unsigned short)(f2u(lo) >> 16);
                }
            }
        } else {  // V -> V^T[i][t]
#pragma unroll
            for (int nt = 0; nt < 2; ++nt){
                const f32x4 cv = nt ? C1 : C0;
                const int i = nt*16 + n15;
#pragma unroll
                for (int r = 0; r < 4; ++r){
                    const int t = q*4 + r;
                    const float v = cv[r];
                    const unsigned u = f2u(v);
                    const float lo = v - u2f(u & 0xffff0000u);
                    r1[0    + i*40 + t] = (unsigned short)(u >> 16);
                    r1[1280 + i*40 + t] = (unsigned short)(f2u(lo) >> 16);
                }
            }
        }
    } else {  // wave 3: zero V^T t=16..31 (guards 0*NaN in O-GEMM k-tail)
        const int plane = lane >> 5, row = lane & 31;
        unsigned short* dst = &r1[plane*1280 + row*40 + 16];
#pragma unroll
        for (int k = 0; k < 8; ++k) *(unsigned*)&dst[2*k] = 0u;
    }
    __syncthreads();

    // ---- P2: wave 0: S = Q@K^T + in-register softmax -> S' split planes ----
    if (w == 0){
        const i32x4 ah = *(const i32x4*)&r0[1280 + n15*40 + q*8];
        const i32x4 al = *(const i32x4*)&r0[1920 + n15*40 + q*8];
        const i32x4 bh = *(const i32x4*)&r0[2560 + n15*40 + q*8];
        const i32x4 bl = *(const i32x4*)&r0[3200 + n15*40 + q*8];
        f32x4 Sc = {0,0,0,0};
        Sc = mfma16(ah, bh, Sc); Sc = mfma16(ah, bl, Sc); Sc = mfma16(al, bh, Sc);
        const bool valid = (n15 < 10);
#pragma unroll
        for (int r = 0; r < 4; ++r){
            float v = valid ? Sc[r] : -1e30f;
            float m = v;
            m = fmaxf(m, __shfl_xor(m, 1)); m = fmaxf(m, __shfl_xor(m, 2));
            m = fmaxf(m, __shfl_xor(m, 4)); m = fmaxf(m, __shfl_xor(m, 8));
            float p = valid ? exp2f((Sc[r] - m)*LOG2E) : 0.f;
            float s = p;
            s += __shfl_xor(s, 1); s += __shfl_xor(s, 2);
            s += __shfl_xor(s, 4); s += __shfl_xor(s, 8);
            const float sp = p / s;
            const int srow = q*4 + r;
            const unsigned u = f2u(sp);
            const float lo = sp - u2f(u & 0xffff0000u);
            r1[2560 + srow*40 + n15] = (unsigned short)(u >> 16);
            r1[3200 + srow*40 + n15] = (unsigned short)(f2u(lo) >> 16);
            r1[2560 + srow*40 + 16 + n15] = 0;   // zero k-tail t=16..31
            r1[3200 + srow*40 + 16 + n15] = 0;
        }
    }
    __syncthreads();

    // ---- P4: O = S'@V (waves 0,1) -> xa transposed; waves 2,3 zero cols 10..63 ----
    if (w < 2){
        const i32x4 ah = *(const i32x4*)&r1[2560 + n15*40 + q*8];
        const i32x4 al = *(const i32x4*)&r1[3200 + n15*40 + q*8];
        const i32x4 bh = *(const i32x4*)&r1[0    + (w*16 + n15)*40 + q*8];
        const i32x4 bl = *(const i32x4*)&r1[1280 + (w*16 + n15)*40 + q*8];
        f32x4 O = {0,0,0,0};
        O = mfma16(ah, bh, O); O = mfma16(ah, bl, O); O = mfma16(al, bh, O);
        const int ig = w*16 + n15;
#pragma unroll
        for (int r = 0; r < 4; ++r){
            const int s = q*4 + r;
            if (s < 10){
                const float v = O[r];
                const unsigned u = f2u(v);
                const float lo = v - u2f(u & 0xffff0000u);
                xap[0][ig][s] = (unsigned short)(u >> 16);
                xap[1][ig][s] = (unsigned short)(f2u(lo) >> 16);
            }
        }
    } else {
        const int lane2 = tid & 127;
        const int plane = lane2 >> 6, row = (lane2 >> 1) & 31, half = lane2 & 1;
        unsigned short* dst = &xap[plane][row][10 + half*27];
#pragma unroll
        for (int c = 0; c < 27; ++c) dst[c] = 0;
    }
    __syncthreads();

    unsigned short (*xh)[72] = xap[0];
    unsigned short (*xl)[72] = xap[1];
    unsigned short* hh_w = &hT[w][0][0][0];
    unsigned short* hl_w = &hT[w][1][0][0];
    float* esw = es_l[w];
    float* edw = ed_l[w];
    gat_layer<1>(tid, xh, xl, hh_w, hl_w, esw, edw, Ap, ws, 0, b1);
    __syncthreads();
    gat_layer<2>(tid, xh, xl, hh_w, hl_w, esw, edw, Ap, ws, 1, b2);
    __syncthreads();
    gat_layer<2>(tid, xh, xl, hh_w, hl_w, esw, edw, Ap, ws, 2, b3);
    __syncthreads();
    gat_layer<2>(tid, xh, xl, hh_w, hl_w, esw, edw, Ap, ws, 3, b4);
    __syncthreads();

    // mean pool (reconstruct hi+lo) + FC(64->2) + softmax
    if (tid < 64){
        float acc = 0.f;
#pragma unroll
        for (int n = 0; n < 32; ++n)
            acc += u2f(((unsigned)xap[0][n][tid]) << 16) + u2f(((unsigned)xap[1][n][tid]) << 16);
        const float p = acc*(1.f/32.f);
        float c0 = p*__ldg(fcW + 2*tid);
        float c1 = p*__ldg(fcW + 2*tid + 1);
#pragma unroll
        for (int off = 32; off > 0; off >>= 1){
            c0 += __shfl_down(c0, off);
            c1 += __shfl_down(c1, off);
        }
        if (tid == 0){
            const float l0 = c0 + __ldg(fcb), l1 = c1 + __ldg(fcb + 1);
            const float m = fmaxf(l0, l1);
            const float e0 = __expf(l0 - m), e1 = __expf(l1 - m);
            const float inv = 1.f/(e0 + e1);
            out[2*g] = l0;
            out[2*g + 1] = l1;
            out[2*NGRAPH + 2*g] = e0*inv;
            out[2*NGRAPH + 2*g + 1] = e1*inv;
        }
    }
}

// prep: split-bf16 W^T planes, shared esed tiles, and QKV^T planes into d_ws.
__global__ void prep(
    const float* __restrict__ W1, const float* __restrict__ W2,
    const float* __restrict__ W3, const float* __restrict__ W4,
    const float* __restrict__ a1s, const float* __restrict__ a1d,
    const float* __restrict__ a2s, const float* __restrict__ a2d,
    const float* __restrict__ a3s, const float* __restrict__ a3d,
    const float* __restrict__ a4s, const float* __restrict__ a4d,
    const float* __restrict__ Wq, const float* __restrict__ Wk,
    const float* __restrict__ Wv,
    char* __restrict__ ws)
{
    const int b = blockIdx.x, tid = threadIdx.x;
    const float* Wl[4] = {W1, W2, W3, W4};
    const int Kl[4] = {10, 64, 64, 64};
    if (b < 32){
        const int l = b >> 3;
        const float* W = Wl[l];
        const int K = Kl[l];
        unsigned short* hi = (unsigned short*)(ws + l*16384);
        unsigned short* lo = hi + 4096;
        const int base = (b & 7)*512;
        for (int idx = base + tid; idx < base + 512; idx += NT){
            const int n = idx >> 6, k = idx & 63;
            const float v = (k < K) ? __ldg(W + k*64 + n) : 0.f;
            const unsigned u = f2u(v);
            const float lof = v - u2f(u & 0xffff0000u);
            hi[idx] = (unsigned short)(u >> 16);
            lo[idx] = (unsigned short)(f2u(lof) >> 16);
        }
    } else if (b < 36){
        const int l = b - 32;
        const float* W = Wl[l];
        const int K = Kl[l];
        const float* asp[4] = {a1s, a2s, a3s, a4s};
        const float* adp[4] = {a1d, a2d, a3d, a4d};
        const int C = (l < 3) ? 16 : 64;
        unsigned short* basep = (unsigned short*)(ws + 65536 + l*4096);
        for (int idx = tid; idx < 1024; idx += NT){
            const int n = idx >> 6, k = idx & 63;   // row n: 2h=was'_h, 2h+1=wad'_h
            float val = 0.f;
            if (n < 8 && k < K){
                const int hh = (l < 3) ? (n >> 1) : 0;
                const float* av = (n & 1) ? adp[l] : asp[l];
                float s = 0.f;
                for (int c = 0; c < C; ++c)
                    s += __ldg(W + k*64 + hh*C + c) * __ldg(av + hh*C + c);
                val = s * LOG2E;
            }
            const unsigned u = f2u(val);
            const float lof = val - u2f(u & 0xffff0000u);
            basep[idx]        = (unsigned short)(u >> 16);
            basep[1024 + idx] = (unsigned short)(f2u(lof) >> 16);
        }
    } else {
        const int mat = b - 36;
        const float* W = (mat == 0) ? Wq : ((mat == 1) ? Wk : Wv);
        unsigned short* hi = (unsigned short*)(ws + 81920 + mat*4096);
        unsigned short* lo = hi + 1024;
        for (int idx = tid; idx < 1024; idx += NT){
            const int i = idx >> 5, m = idx & 31;
            const float v = __ldg(W + m*32 + i);
            const unsigned u = f2u(v);
            const float lof = v - u2f(u & 0xffff0000u);
            hi[idx] = (unsigned short)(u >> 16);
            lo[idx] = (unsigned short)(f2u(lof) >> 16);
        }
    }
}

extern "C" void kernel_launch(void* const* d_in, const int* in_sizes, int n_in,
                              void* d_out, int out_size, void* d_ws, size_t ws_size,
                              hipStream_t stream) {
    (void)in_sizes; (void)n_in; (void)ws_size; (void)out_size;
    prep<<<39, NT, 0, stream>>>(
        (const float*)d_in[6], (const float*)d_in[10], (const float*)d_in[14], (const float*)d_in[18],
        (const float*)d_in[7], (const float*)d_in[8],
        (const float*)d_in[11], (const float*)d_in[12],
        (const float*)d_in[15], (const float*)d_in[16],
        (const float*)d_in[19], (const float*)d_in[20],
        (const float*)d_in[3], (const float*)d_in[4], (const float*)d_in[5],
        (char*)d_ws);
    gnn_fused<<<NGRAPH, NT, 0, stream>>>(
        (const float*)d_in[0], (const int*)d_in[1],
        (const float*)d_in[9], (const float*)d_in[13], (const float*)d_in[17], (const float*)d_in[21],
        (const float*)d_in[22], (const float*)d_in[23],
        (const char*)d_ws, (float*)d_out);
}

// Round 14
// 198.410 us; speedup vs baseline: 1.1407x; 1.0239x over previous
//
#include <hip/hip_runtime.h>

// Fused GNN forward for mynet_30039001268550 on gfx950 — round 14.
// = R12 (93 us, passing: MFMA front-end + all-MFMA GAT layers, hT LDS
// round-trip for the stage-B B-frag) + low-risk polish:
//  - pack-h stores b64-packed (4x uint2 vs 16x u16 per lane)
//  - V^T stores b64-packed
//  - b64 zero-fill of xa cols 10..63
//  - epilogue 1/ssum reads as f32x4
// R13's ds_bpermute in-register transpose is REVERTED (failed on silicon
// with absmax 0.398 despite 4x-verified index math — root cause unknown;
// retry via __shfl as an isolated variable later).

#define NGRAPH 4096
#define EDGES  (NGRAPH * 256)
#define NT     256
#define LOG2E  1.4426950408889634f

typedef __attribute__((ext_vector_type(8))) short bf16x8;
typedef __attribute__((ext_vector_type(4))) float f32x4;
typedef __attribute__((ext_vector_type(4))) int   i32x4;

__device__ __forceinline__ unsigned f2u(float x){ union{float f;unsigned u;}c;c.f=x;return c.u; }
__device__ __forceinline__ float u2f(unsigned u){ union{unsigned u;float f;}c;c.u=u;return c.f; }

__device__ __forceinline__ void split2(float x0, float x1, unsigned& dhi, unsigned& dlo){
    const unsigned u0 = f2u(x0), u1 = f2u(x1);
    dhi = (u0 >> 16) | (u1 & 0xffff0000u);
    const float l0 = x0 - u2f(u0 & 0xffff0000u);
    const float l1 = x1 - u2f(u1 & 0xffff0000u);
    dlo = (f2u(l0) >> 16) | (f2u(l1) & 0xffff0000u);
}

__device__ __forceinline__ f32x4 mfma16(i32x4 a, i32x4 b, f32x4 c){
    return __builtin_amdgcn_mfma_f32_16x16x32_bf16(
        __builtin_bit_cast(bf16x8, a), __builtin_bit_cast(bf16x8, b), c, 0, 0, 0);
}

// ws layout (bytes), total 94208 <= proven-safe 131072:
//   0     : Wt planes per layer l at l*16384: hi [64n][64k] bf16, lo +8192
//   65536 : esed shared tile per layer at 65536+l*4096: hi [16n][64k], lo +2048
//           rows 2h -> was'_h*log2e, 2h+1 -> wad'_h*log2e (l=3: head 0 dup), rest 0
//   81920 : QKV^T planes per mat at 81920+mat*4096: hi [32 i][32 m], lo +2048
template<int KSTEPS>
__device__ __forceinline__ void gat_layer(
    int tid, unsigned short (*xh)[72], unsigned short (*xl)[72],
    unsigned short* hh_w, unsigned short* hl_w, float* esw, float* edw,
    const unsigned int* Ap, const char* __restrict__ ws, int l,
    const float* __restrict__ b_g)
{
    const int lane = tid & 63, w = tid >> 6;
    const int n15 = lane & 15, q = lane >> 4;

    // ---- stage A: h = xa@W and es/ed (all heads) = xa@esed-tile on MFMA ----
    f32x4 hC0 = {0,0,0,0}, hC1 = {0,0,0,0};
    f32x4 eC0 = {0,0,0,0}, eC1 = {0,0,0,0};
#pragma unroll
    for (int ks = 0; ks < KSTEPS; ++ks){
        const unsigned short* wr = (const unsigned short*)(ws + l*16384)
                                   + (w*16 + n15)*64 + ks*32 + q*8;
        const i32x4 bh = *(const i32x4*)wr;
        const i32x4 bl = *(const i32x4*)(wr + 4096);
        const unsigned short* er = (const unsigned short*)(ws + 65536 + l*4096)
                                   + n15*64 + ks*32 + q*8;
        const i32x4 eh = *(const i32x4*)er;
        const i32x4 el = *(const i32x4*)(er + 1024);

        const i32x4 a0h = *(const i32x4*)&xh[n15][ks*32 + q*8];
        const i32x4 a0l = *(const i32x4*)&xl[n15][ks*32 + q*8];
        hC0 = mfma16(a0h, bh, hC0); hC0 = mfma16(a0h, bl, hC0); hC0 = mfma16(a0l, bh, hC0);
        eC0 = mfma16(a0h, eh, eC0); eC0 = mfma16(a0h, el, eC0); eC0 = mfma16(a0l, eh, eC0);

        const i32x4 a1h = *(const i32x4*)&xh[16 + n15][ks*32 + q*8];
        const i32x4 a1l = *(const i32x4*)&xl[16 + n15][ks*32 + q*8];
        hC1 = mfma16(a1h, bh, hC1); hC1 = mfma16(a1h, bl, hC1); hC1 = mfma16(a1l, bh, hC1);
        eC1 = mfma16(a1h, eh, eC1); eC1 = mfma16(a1h, el, eC1); eC1 = mfma16(a1l, eh, eC1);
    }
    __syncthreads();   // all xa reads done; wave-local work + xa writes follow

    // ---- scatter es/ed: this wave's head lives in C-columns 2w (es), 2w+1 (ed) ----
    if (n15 == 2*w || n15 == 2*w + 1){
        float* dst = (n15 & 1) ? edw : esw;
#pragma unroll
        for (int r = 0; r < 4; ++r){
            dst[q*4 + r]      = eC0[r];
            dst[16 + q*4 + r] = eC1[r];
        }
    }

    // ---- pack h (hi/lo bf16 planes, [n][k=j] order), b64-packed stores ----
#pragma unroll
    for (int mt = 0; mt < 2; ++mt){
        const f32x4 hv = mt ? hC1 : hC0;
        unsigned h0, l0v, h1, l1v;
        split2(hv[0], hv[1], h0, l0v);
        split2(hv[2], hv[3], h1, l1v);
        *(uint2*)&hh_w[n15*40 + mt*16 + q*4] = make_uint2(h0, h1);
        *(uint2*)&hl_w[n15*40 + mt*16 + q*4] = make_uint2(l0v, l1v);
    }

    // ---- p build, both m-tiles, directly in A-frag layout (m=n15, k=q*8+jj) ----
    float pf0[8], pf1[8];
    {
        float es8[8];
        *(float4*)&es8[0] = *(const float4*)&esw[q*8];
        *(float4*)&es8[4] = *(const float4*)&esw[q*8 + 4];
        const float ed0 = edw[n15], ed1 = edw[16 + n15];
        const uint2 c0 = make_uint2(Ap[n15*9 + 2*q], Ap[n15*9 + 2*q + 1]);
        const uint2 c1 = make_uint2(Ap[(16+n15)*9 + 2*q], Ap[(16+n15)*9 + 2*q + 1]);
        float ss0 = 0.f, ss1 = 0.f;
#pragma unroll
        for (int jj = 0; jj < 8; ++jj){
            const unsigned cnt0 = ((jj < 4 ? c0.x >> (8*jj) : c0.y >> (8*(jj-4))) & 0xffu);
            const unsigned cnt1 = ((jj < 4 ? c1.x >> (8*jj) : c1.y >> (8*(jj-4))) & 0xffu);
            float e0 = es8[jj] + ed0; e0 = fmaxf(e0, 0.2f*e0);   // lrelu, log2-domain
            float e1 = es8[jj] + ed1; e1 = fmaxf(e1, 0.2f*e1);
            const float p0 = (float)cnt0 * exp2f(e0);
            const float p1 = (float)cnt1 * exp2f(e1);
            pf0[jj] = p0; ss0 += p0;
            pf1[jj] = p1; ss1 += p1;
        }
        ss0 += __shfl_xor(ss0, 16); ss0 += __shfl_xor(ss0, 32);
        ss1 += __shfl_xor(ss1, 16); ss1 += __shfl_xor(ss1, 32);
        if (q == 0){
            edw[n15]      = 1.f/(ss0 + 1e-16f);
            edw[16 + n15] = 1.f/(ss1 + 1e-16f);
        }
    }

    // ---- stage B: out = P@h via mfma (B-frag = raw b128 from h planes) ----
    {
        const i32x4 bh = *(const i32x4*)&hh_w[n15*40 + q*8];
        const i32x4 bl = *(const i32x4*)&hl_w[n15*40 + q*8];
        f32x4 o0 = {0,0,0,0}, o1 = {0,0,0,0};
        i32x4 ph, pl; unsigned th, tl;
#pragma unroll
        for (int r = 0; r < 4; ++r){
            split2(pf0[2*r], pf0[2*r+1], th, tl); ph[r] = (int)th; pl[r] = (int)tl;
        }
        o0 = mfma16(ph, bh, o0); o0 = mfma16(ph, bl, o0); o0 = mfma16(pl, bh, o0);
#pragma unroll
        for (int r = 0; r < 4; ++r){
            split2(pf1[2*r], pf1[2*r+1], th, tl); ph[r] = (int)th; pl[r] = (int)tl;
        }
        o1 = mfma16(ph, bh, o1); o1 = mfma16(ph, bl, o1); o1 = mfma16(pl, bh, o1);

        const float bv = __ldg(b_g + w*16 + n15);
        const f32x4 iv0 = *(const f32x4*)&edw[q*4];
        const f32x4 iv1 = *(const f32x4*)&edw[16 + q*4];
#pragma unroll
        for (int mt = 0; mt < 2; ++mt){
            const f32x4 ov = mt ? o1 : o0;
            const f32x4 iv = mt ? iv1 : iv0;
#pragma unroll
            for (int r = 0; r < 4; ++r){
                const int row = mt*16 + q*4 + r;
                float v = ov[r] * iv[r] + bv;
                v = fmaxf(v, 0.01f*v);
                const unsigned u = f2u(v);
                const float lo = v - u2f(u & 0xffff0000u);
                xh[row][w*16 + n15] = (unsigned short)(u >> 16);
                xl[row][w*16 + n15] = (unsigned short)(f2u(lo) >> 16);
            }
        }
    }
}

__global__ __launch_bounds__(NT) void gnn_fused(
    const float* __restrict__ x, const int* __restrict__ edge_index,
    const float* __restrict__ b1, const float* __restrict__ b2,
    const float* __restrict__ b3, const float* __restrict__ b4,
    const float* __restrict__ fcW, const float* __restrict__ fcb,
    const char* __restrict__ ws, float* __restrict__ out)
{
    __shared__ __align__(16) unsigned short xap[2][32][72]; // bf16 hi/lo feature planes
    __shared__ __align__(16) unsigned short hT[4][2][16][40]; // per-wave h planes / attn scratch
    __shared__ __align__(16) float es_l[4][32];
    __shared__ __align__(16) float ed_l[4][32];
    __shared__ __align__(16) unsigned int Ap[32*9];  // packed u8 edge counts

    const int g = blockIdx.x, tid = threadIdx.x;
    const int lane = tid & 63, w = tid >> 6;
    const int n15 = lane & 15, q = lane >> 4;

    // front-end overlays (short offsets)
    unsigned short* r0 = &xap[0][0][0];   // XTH 0 [16s][40m], XTL 640, QPH 1280,
                                          // QPL 1920, KPH 2560, KPL 3200 (<=4608)
    unsigned short* r1 = &hT[0][0][0][0]; // VTH 0 [32i][40t], VTL 1280,
                                          // SPH 2560 [16s][40t], SPL 3200

    // ---- phase 0: zero Ap, stage x^T (split-bf16), zero x^T rows 10..15 ----
    for (int idx = tid; idx < 288; idx += NT) Ap[idx] = 0u;
    for (int idx = tid; idx < 320; idx += NT){
        const int m = idx / 10, s = idx - 10*m;   // m = node, s = feat
        const float v = x[g*320 + idx];
        const unsigned u = f2u(v);
        const float lo = v - u2f(u & 0xffff0000u);
        r0[0   + s*40 + m] = (unsigned short)(u >> 16);
        r0[640 + s*40 + m] = (unsigned short)(f2u(lo) >> 16);
    }
    if (tid < 192){   // stale-LDS guard: rows 10..15 feed the QKV A-fragment
        const int s = 10 + (tid >> 5), m = tid & 31;
        r0[0   + s*40 + m] = 0;
        r0[640 + s*40 + m] = 0;
    }
    __syncthreads();

    // ---- P1: edge-count packed atomics + Q/K/V MFMA + V^T tail zero ----
    {
        const int* dstp = edge_index + EDGES + g*256;
        const int i = dstp[tid] & 31, j = tid >> 3;
        atomicAdd(&Ap[i*9 + (j >> 2)], 1u << (8*(j & 3)));
        if (tid < 32) atomicAdd(&Ap[tid*9 + (tid >> 2)], 1u << (8*(tid & 3)));
    }
    if (w < 3){
        const unsigned short* wb = (const unsigned short*)(ws + 81920 + w*4096);
        const i32x4 ah = *(const i32x4*)&r0[0   + n15*40 + q*8];
        const i32x4 al = *(const i32x4*)&r0[640 + n15*40 + q*8];
        f32x4 C0 = {0,0,0,0}, C1 = {0,0,0,0};
#pragma unroll
        for (int nt = 0; nt < 2; ++nt){
            const i32x4 bh = *(const i32x4*)&wb[(nt*16 + n15)*32 + q*8];
            const i32x4 bl = *(const i32x4*)&wb[1024 + (nt*16 + n15)*32 + q*8];
            f32x4 acc = nt ? C1 : C0;
            acc = mfma16(ah, bh, acc); acc = mfma16(ah, bl, acc); acc = mfma16(al, bh, acc);
            if (nt) C1 = acc; else C0 = acc;
        }
        if (w < 2){
            const int base = (w == 0) ? 1280 : 2560;  // QPH : KPH
#pragma unroll
            for (int nt = 0; nt < 2; ++nt){
                const f32x4 cv = nt ? C1 : C0;
                const int i = nt*16 + n15;
#pragma unroll
                for (int r = 0; r < 4; ++r){
                    const int s = q*4 + r;
                    const float v = cv[r];
                    const unsigned u = f2u(v);
                    const float lo = v - u2f(u & 0xffff0000u);
                    r0[base + s*40 + i]       = (unsigned short)(u >> 16);
                    r0[base + 640 + s*40 + i] = (unsigned short)(f2u(lo) >> 16);
                }
            }
        } else {  // V -> V^T[i][t], b64-packed (t = q*4..q*4+3 consecutive)
#pragma unroll
            for (int nt = 0; nt < 2; ++nt){
                const f32x4 cv = nt ? C1 : C0;
                const int i = nt*16 + n15;
                unsigned h0, l0v, h1, l1v;
                split2(cv[0], cv[1], h0, l0v);
                split2(cv[2], cv[3], h1, l1v);
                *(uint2*)&r1[0    + i*40 + q*4] = make_uint2(h0, h1);
                *(uint2*)&r1[1280 + i*40 + q*4] = make_uint2(l0v, l1v);
            }
        }
    } else {  // wave 3: zero V^T t=16..31 (guards 0*NaN in O-GEMM k-tail)
        const int plane = lane >> 5, row = lane & 31;
        unsigned short* dst = &r1[plane*1280 + row*40 + 16];
#pragma unroll
        for (int k = 0; k < 4; ++k) *(unsigned long long*)&dst[4*k] = 0ull;
    }
    __syncthreads();

    // ---- P2: wave 0: S = Q@K^T + in-register softmax -> S' split planes ----
    if (w == 0){
        const i32x4 ah = *(const i32x4*)&r0[1280 + n15*40 + q*8];
        const i32x4 al = *(const i32x4*)&r0[1920 + n15*40 + q*8];
        const i32x4 bh = *(const i32x4*)&r0[2560 + n15*40 + q*8];
        const i32x4 bl = *(const i32x4*)&r0[3200 + n15*40 + q*8];
        f32x4 Sc = {0,0,0,0};
        Sc = mfma16(ah, bh, Sc); Sc = mfma16(ah, bl, Sc); Sc = mfma16(al, bh, Sc);
        const bool valid = (n15 < 10);
#pragma unroll
        for (int r = 0; r < 4; ++r){
            float v = valid ? Sc[r] : -1e30f;
            float m = v;
            m = fmaxf(m, __shfl_xor(m, 1)); m = fmaxf(m, __shfl_xor(m, 2));
            m = fmaxf(m, __shfl_xor(m, 4)); m = fmaxf(m, __shfl_xor(m, 8));
            float p = valid ? exp2f((Sc[r] - m)*LOG2E) : 0.f;
            float s = p;
            s += __shfl_xor(s, 1); s += __shfl_xor(s, 2);
            s += __shfl_xor(s, 4); s += __shfl_xor(s, 8);
            const float sp = p / s;
            const int srow = q*4 + r;
            const unsigned u = f2u(sp);
            const float lo = sp - u2f(u & 0xffff0000u);
            r1[2560 + srow*40 + n15] = (unsigned short)(u >> 16);
            r1[3200 + srow*40 + n15] = (unsigned short)(f2u(lo) >> 16);
            r1[2560 + srow*40 + 16 + n15] = 0;   // zero k-tail t=16..31
            r1[3200 + srow*40 + 16 + n15] = 0;
        }
    }
    __syncthreads();

    // ---- P4: O = S'@V (waves 0,1) -> xa transposed; waves 2,3 zero cols 10..63 ----
    if (w < 2){
        const i32x4 ah = *(const i32x4*)&r1[2560 + n15*40 + q*8];
        const i32x4 al = *(const i32x4*)&r1[3200 + n15*40 + q*8];
        const i32x4 bh = *(const i32x4*)&r1[0    + (w*16 + n15)*40 + q*8];
        const i32x4 bl = *(const i32x4*)&r1[1280 + (w*16 + n15)*40 + q*8];
        f32x4 O = {0,0,0,0};
        O = mfma16(ah, bh, O); O = mfma16(ah, bl, O); O = mfma16(al, bh, O);
        const int ig = w*16 + n15;
#pragma unroll
        for (int r = 0; r < 4; ++r){
            const int s = q*4 + r;
            if (s < 10){
                const float v = O[r];
                const unsigned u = f2u(v);
                const float lo = v - u2f(u & 0xffff0000u);
                xap[0][ig][s] = (unsigned short)(u >> 16);
                xap[1][ig][s] = (unsigned short)(f2u(lo) >> 16);
            }
        }
    } else {
        const int idx = tid - 128;               // 0..127
        const int plane = idx >> 6, row = (idx >> 1) & 31, half = idx & 1;
        unsigned short* rowp = plane ? &xap[1][row][0] : &xap[0][row][0];
        if (half == 0){
            *(unsigned*)&rowp[10] = 0u;          // cols 10-11
#pragma unroll
            for (int c = 0; c < 6; ++c) *(unsigned long long*)&rowp[12 + 4*c] = 0ull;
        } else {
#pragma unroll
            for (int c = 0; c < 7; ++c) *(unsigned long long*)&rowp[36 + 4*c] = 0ull;
        }
    }
    __syncthreads();

    unsigned short (*xh)[72] = xap[0];
    unsigned short (*xl)[72] = xap[1];
    unsigned short* hh_w = &hT[w][0][0][0];
    unsigned short* hl_w = &hT[w][1][0][0];
    float* esw = es_l[w];
    float* edw = ed_l[w];
    gat_layer<1>(tid, xh, xl, hh_w, hl_w, esw, edw, Ap, ws, 0, b1);
    __syncthreads();
    gat_layer<2>(tid, xh, xl, hh_w, hl_w, esw, edw, Ap, ws, 1, b2);
    __syncthreads();
    gat_layer<2>(tid, xh, xl, hh_w, hl_w, esw, edw, Ap, ws, 2, b3);
    __syncthreads();
    gat_layer<2>(tid, xh, xl, hh_w, hl_w, esw, edw, Ap, ws, 3, b4);
    __syncthreads();

    // mean pool (reconstruct hi+lo) + FC(64->2) + softmax
    if (tid < 64){
        float acc = 0.f;
#pragma unroll
        for (int n = 0; n < 32; ++n)
            acc += u2f(((unsigned)xap[0][n][tid]) << 16) + u2f(((unsigned)xap[1][n][tid]) << 16);
        const float p = acc*(1.f/32.f);
        float c0 = p*__ldg(fcW + 2*tid);
        float c1 = p*__ldg(fcW + 2*tid + 1);
#pragma unroll
        for (int off = 32; off > 0; off >>= 1){
            c0 += __shfl_down(c0, off);
            c1 += __shfl_down(c1, off);
        }
        if (tid == 0){
            const float l0 = c0 + __ldg(fcb), l1 = c1 + __ldg(fcb + 1);
            const float m = fmaxf(l0, l1);
            const float e0 = __expf(l0 - m), e1 = __expf(l1 - m);
            const float inv = 1.f/(e0 + e1);
            out[2*g] = l0;
            out[2*g + 1] = l1;
            out[2*NGRAPH + 2*g] = e0*inv;
            out[2*NGRAPH + 2*g + 1] = e1*inv;
        }
    }
}

// prep: split-bf16 W^T planes, shared esed tiles, and QKV^T planes into d_ws.
__global__ void prep(
    const float* __restrict__ W1, const float* __restrict__ W2,
    const float* __restrict__ W3, const float* __restrict__ W4,
    const float* __restrict__ a1s, const float* __restrict__ a1d,
    const float* __restrict__ a2s, const float* __restrict__ a2d,
    const float* __restrict__ a3s, const float* __restrict__ a3d,
    const float* __restrict__ a4s, const float* __restrict__ a4d,
    const float* __restrict__ Wq, const float* __restrict__ Wk,
    const float* __restrict__ Wv,
    char* __restrict__ ws)
{
    const int b = blockIdx.x, tid = threadIdx.x;
    const float* Wl[4] = {W1, W2, W3, W4};
    const int Kl[4] = {10, 64, 64, 64};
    if (b < 32){
        const int l = b >> 3;
        const float* W = Wl[l];
        const int K = Kl[l];
        unsigned short* hi = (unsigned short*)(ws + l*16384);
        unsigned short* lo = hi + 4096;
        const int base = (b & 7)*512;
        for (int idx = base + tid; idx < base + 512; idx += NT){
            const int n = idx >> 6, k = idx & 63;
            const float v = (k < K) ? __ldg(W + k*64 + n) : 0.f;
            const unsigned u = f2u(v);
            const float lof = v - u2f(u & 0xffff0000u);
            hi[idx] = (unsigned short)(u >> 16);
            lo[idx] = (unsigned short)(f2u(lof) >> 16);
        }
    } else if (b < 36){
        const int l = b - 32;
        const float* W = Wl[l];
        const int K = Kl[l];
        const float* asp[4] = {a1s, a2s, a3s, a4s};
        const float* adp[4] = {a1d, a2d, a3d, a4d};
        const int C = (l < 3) ? 16 : 64;
        unsigned short* basep = (unsigned short*)(ws + 65536 + l*4096);
        for (int idx = tid; idx < 1024; idx += NT){
            const int n = idx >> 6, k = idx & 63;   // row n: 2h=was'_h, 2h+1=wad'_h
            float val = 0.f;
            if (n < 8 && k < K){
                const int hh = (l < 3) ? (n >> 1) : 0;
                const float* av = (n & 1) ? adp[l] : asp[l];
                float s = 0.f;
                for (int c = 0; c < C; ++c)
                    s += __ldg(W + k*64 + hh*C + c) * __ldg(av + hh*C + c);
                val = s * LOG2E;
            }
            const unsigned u = f2u(val);
            const float lof = val - u2f(u & 0xffff0000u);
            basep[idx]        = (unsigned short)(u >> 16);
            basep[1024 + idx] = (unsigned short)(f2u(lof) >> 16);
        }
    } else {
        const int mat = b - 36;
        const float* W = (mat == 0) ? Wq : ((mat == 1) ? Wk : Wv);
        unsigned short* hi = (unsigned short*)(ws + 81920 + mat*4096);
        unsigned short* lo = hi + 1024;
        for (int idx = tid; idx < 1024; idx += NT){
            const int i = idx >> 5, m = idx & 31;
            const float v = __ldg(W + m*32 + i);
            const unsigned u = f2u(v);
            const float lof = v - u2f(u & 0xffff0000u);
            hi[idx] = (unsigned short)(u >> 16);
            lo[idx] = (unsigned short)(f2u(lof) >> 16);
        }
    }
}

extern "C" void kernel_launch(void* const* d_in, const int* in_sizes, int n_in,
                              void* d_out, int out_size, void* d_ws, size_t ws_size,
                              hipStream_t stream) {
    (void)in_sizes; (void)n_in; (void)ws_size; (void)out_size;
    prep<<<39, NT, 0, stream>>>(
        (const float*)d_in[6], (const float*)d_in[10], (const float*)d_in[14], (const float*)d_in[18],
        (const float*)d_in[7], (const float*)d_in[8],
        (const float*)d_in[11], (const float*)d_in[12],
        (const float*)d_in[15], (const float*)d_in[16],
        (const float*)d_in[19], (const float*)d_in[20],
        (const float*)d_in[3], (const float*)d_in[4], (const float*)d_in[5],
        (char*)d_ws);
    gnn_fused<<<NGRAPH, NT, 0, stream>>>(
        (const float*)d_in[0], (const int*)d_in[1],
        (const float*)d_in[9], (const float*)d_in[13], (const float*)d_in[17], (const float*)d_in[21],
        (const float*)d_in[22], (const float*)d_in[23],
        (const char*)d_ws, (float*)d_out);
}